// Round 12
// baseline (205.699 us; speedup 1.0000x reference)
//
#include <hip/hip_runtime.h>
#include <hip/hip_bf16.h>

// BatchTripletLoss on MI355X — round 12: R10 + B-fragments direct from global.
// Units: 256x128 (bm<32, bn in [2bm,64) -> 1056), 8 waves (4M x 2N), 64x64/wave,
// BK=32 A-only double-buffer (32KB LDS), 2 blocks/CU. B-tile (8KB/KT) is read
// straight from global into MFMA frags: L1-resident, 4x reuse across wm-waves —
// removes 40KB/block-KT from the binding LDS pipe (88->48KB). bf(kt+1) prefetched
// into regs before the sync so HBM/L2 latency hides under current-KT MFMAs.

#define NROWS 8192
#define DIM   1024
#define BTM   256
#define BTN   128
#define BK    32
#define NKT   (DIM / BK)            // 32 K-tiles
#define NUNITS 1056                 // sum_{bm<32} (64 - 2*bm)

constexpr float EPS = 1e-6f;
constexpr float MARGIN = 0.5f;

typedef __attribute__((ext_vector_type(8))) short short8;
typedef __attribute__((ext_vector_type(4))) float f32x4;

__device__ __forceinline__ unsigned short f2bf_rne(float f) {
    unsigned u = __float_as_uint(f);
    u += 0x7fffu + ((u >> 16) & 1u);
    return (unsigned short)(u >> 16);
}

// ---------------- kernel 1: per-row stats + bf16 conversion ----------------
__global__ void prep_kernel(const float* __restrict__ X, const float* __restrict__ P,
                            unsigned short* __restrict__ Xb,
                            float* __restrict__ cj, float* __restrict__ basei,
                            float* __restrict__ posd, int* __restrict__ valid)
{
    const int tid  = threadIdx.x;
    const int w    = tid >> 6;
    const int lane = tid & 63;
    const int row  = blockIdx.x * 4 + w;
    const float* xr = X + (size_t)row * DIM;

    float sq = 0.f, sm = 0.f, pd = 0.f;
    bool eq = true;
    #pragma unroll
    for (int it = 0; it < 4; ++it) {
        const int idx = it * 256 + lane * 4;
        const float4 x = *(const float4*)(xr + idx);
        const float4 p = *(const float4*)(P + idx);
        sq += x.x*x.x + x.y*x.y + x.z*x.z + x.w*x.w;
        sm += x.x + x.y + x.z + x.w;
        const float d0 = x.x - p.x + EPS, d1 = x.y - p.y + EPS;
        const float d2 = x.z - p.z + EPS, d3 = x.w - p.w + EPS;
        pd += d0*d0 + d1*d1 + d2*d2 + d3*d3;
        eq = eq && (x.x == p.x) && (x.y == p.y) && (x.z == p.z) && (x.w == p.w);
        ushort4 b;
        b.x = f2bf_rne(x.x); b.y = f2bf_rne(x.y); b.z = f2bf_rne(x.z); b.w = f2bf_rne(x.w);
        *(ushort4*)(Xb + (size_t)row * DIM + idx) = b;
    }
    #pragma unroll
    for (int off = 32; off >= 1; off >>= 1) {
        sq += __shfl_xor(sq, off);
        sm += __shfl_xor(sm, off);
        pd += __shfl_xor(pd, off);
    }
    const bool alleq = __all(eq);
    if (lane == 0) {
        cj[row]    = sq - 2.f * EPS * sm;
        basei[row] = sq + 2.f * EPS * sm + (float)DIM * EPS * EPS;
        posd[row]  = sqrtf(pd);
        valid[row] = alleq ? 0 : 1;
    }
}

// ---------------- kernel 2: co-resident symmetric GEMM + row/col max ----------------
// LDS per buf: A only = 256x32 = 1024 chunks of 16B (16KB). Swizzle: logical (r,c)
// chunk at phys p = r*4 + (c ^ ((r>>1)&3)); gload_lds writes phys-linear, source
// pre-permuted (thread q -> row q>>2, K-chunk (q&3)^((q>>3)&3)). Frag reads:
// cx = lk ^ ((l15>>1)&3) -> conflict-free (verified R10: 0 conflicts).
// B-frags: direct global, addr = (Nbase + wn*64 + nt*16 + l15)*DIM + kt*32 + lk*8.
__global__ __launch_bounds__(512, 4) void gemm_max_kernel(
        const unsigned short* __restrict__ Xb,
        const float* __restrict__ cj,
        float* __restrict__ partmax)
{
    __shared__ alignas(16) unsigned short lds[2][1024 * 8];   // [buf][A: 1024 chunks]

    const int tid  = threadIdx.x;
    const int lane = tid & 63;
    const int wid  = tid >> 6;        // 0..7
    const int wm   = wid >> 1;        // 0..3  (64-row strip)
    const int wn   = wid & 1;         // 0..1  (64-col strip)
    const int l15  = lane & 15;
    const int lk   = lane >> 4;       // 0..3
    const int cx   = lk ^ ((l15 >> 1) & 3);

    // XCD-chunked bijective unit decode (1056 = 8 * 132); base(bm) = 65*bm - bm*bm
    const int t0 = (blockIdx.x & 7) * (NUNITS / 8) + (blockIdx.x >> 3);
    int bm = (int)(32.5f - sqrtf(1056.25f - (float)t0));
    if (bm < 0) bm = 0;
    if (bm > 31) bm = 31;
    while (bm > 0 && 65 * bm - bm * bm > t0) --bm;
    while (65 * (bm + 1) - (bm + 1) * (bm + 1) <= t0) ++bm;
    const int bn = 2 * bm + (t0 - (65 * bm - bm * bm));
    const int Mbase = bm * BTM, Nbase = bn * BTN;

    f32x4 acc[4][4];
    #pragma unroll
    for (int m = 0; m < 4; ++m)
        #pragma unroll
        for (int n = 0; n < 4; ++n)
            acc[m][n] = (f32x4){0.f, 0.f, 0.f, 0.f};

    // stage A for one KT into buffer BUF (2 x gload_lds of 16B/thread)
    #define STAGE(BUF, KT) do {                                                               \
        _Pragma("unroll")                                                                     \
        for (int inst_ = 0; inst_ < 2; ++inst_) {                                             \
            const int q_ = inst_ * 512 + tid;                                                 \
            const int r_ = q_ >> 2;                                                           \
            const int c_ = (q_ & 3) ^ ((q_ >> 3) & 3);                                        \
            const unsigned short* src_ = Xb + (size_t)(Mbase + r_) * DIM + (KT) * BK + c_ * 8; \
            unsigned short* dst_ = &lds[BUF][(inst_ * 512 + wid * 64) * 8];                   \
            __builtin_amdgcn_global_load_lds((const __attribute__((address_space(1))) void*)src_, \
                                             (__attribute__((address_space(3))) void*)dst_, 16, 0, 0); \
        }                                                                                     \
    } while (0)

    // per-lane B base pointer (row fixed, K advances with kt)
    const unsigned short* Bg = Xb + (size_t)(Nbase + wn * 64 + l15) * DIM + lk * 8;

    // prologue: stage A(kt0); load bf(kt0); drain
    STAGE(0, 0);
    short8 bfc[4], bfn[4];
    #pragma unroll
    for (int nt = 0; nt < 4; ++nt)
        bfc[nt] = *(const short8*)(Bg + nt * 16 * DIM);
    __syncthreads();

    #pragma unroll 2
    for (int kt = 0; kt < NKT; ++kt) {
        const int b = kt & 1;
        // prefetch A(kt+1) into other buffer and bf(kt+1) into regs
        if (kt + 1 < NKT) {
            STAGE(b ^ 1, kt + 1);
            #pragma unroll
            for (int nt = 0; nt < 4; ++nt)
                bfn[nt] = *(const short8*)(Bg + nt * 16 * DIM + (kt + 1) * BK);
        }

        const unsigned short* Ab = &lds[b][0];
        short8 af[4];
        #pragma unroll
        for (int mt = 0; mt < 4; ++mt)
            af[mt] = *(const short8*)(Ab + (((wm * 64 + mt * 16 + l15) << 2) + cx) * 8);

        __builtin_amdgcn_s_setprio(1);
        #pragma unroll
        for (int mt = 0; mt < 4; ++mt)
            #pragma unroll
            for (int nt = 0; nt < 4; ++nt)
                acc[mt][nt] = __builtin_amdgcn_mfma_f32_16x16x32_bf16(af[mt], bfc[nt], acc[mt][nt], 0, 0, 0);
        __builtin_amdgcn_s_setprio(0);

        __syncthreads();   // drains vmcnt+lgkmcnt; flips buffers
        #pragma unroll
        for (int nt = 0; nt < 4; ++nt) bfc[nt] = bfn[nt];
    }
    #undef STAGE

    // ---- epilogue. C/D layout: col = l15, row = lk*4 + reg.
    // acc[m][n]: row wm*64 + m*16, col wn*64 + n*16. Mask only i==j; both paths always.
    float* scratchf = (float*)&lds[0][0];  // [0..511]: row (wn*256+lrow); [512..1023]: col (wm*128+lcol)
    float cv[4];
    #pragma unroll
    for (int n = 0; n < 4; ++n)
        cv[n] = cj[Nbase + wn * 64 + n * 16 + l15];

    float vt[4];
    #pragma unroll
    for (int n = 0; n < 4; ++n) vt[n] = -__builtin_inff();

    #pragma unroll
    for (int m = 0; m < 4; ++m) {
        #pragma unroll
        for (int r = 0; r < 4; ++r) {
            const int lrow = wm * 64 + m * 16 + lk * 4 + r;
            const int grow = Mbase + lrow;
            const float ci = cj[grow];
            float rv = -__builtin_inff();
            #pragma unroll
            for (int n = 0; n < 4; ++n) {
                const float dot2 = 2.f * acc[m][n][r];
                const bool dg = (grow == Nbase + wn * 64 + n * 16 + l15);
                float vr = cv[n] - dot2;
                float vc = ci - dot2;
                if (dg) { vr = -__builtin_inff(); vc = -__builtin_inff(); }
                rv = fmaxf(rv, vr);
                vt[n] = fmaxf(vt[n], vc);
            }
            #pragma unroll
            for (int off = 8; off >= 1; off >>= 1)
                rv = fmaxf(rv, __shfl_xor(rv, off));
            if (l15 == 0) scratchf[wn * 256 + lrow] = rv;
        }
    }
    #pragma unroll
    for (int n = 0; n < 4; ++n) {
        vt[n] = fmaxf(vt[n], __shfl_xor(vt[n], 16));
        vt[n] = fmaxf(vt[n], __shfl_xor(vt[n], 32));
        if (lk == 0) scratchf[512 + wm * 128 + wn * 64 + n * 16 + l15] = vt[n];
    }
    __syncthreads();

    if (tid < BTM) {
        partmax[(size_t)bn * NROWS + Mbase + tid] = fmaxf(scratchf[tid], scratchf[256 + tid]);
    } else if (tid < BTM + BTN) {
        const int c = tid - BTM;
        const float v = fmaxf(fmaxf(scratchf[512 + c], scratchf[640 + c]),
                              fmaxf(scratchf[768 + c], scratchf[896 + c]));
        partmax[(size_t)(64 + bm) * NROWS + Nbase + c] = v;
    }
}

// ---------------- kernel 3: per-row finalize + block partial sums ----------------
// Row i (strip a = i>>8): row-path slots bn in [2a, 64); col-path slots 64+bm, bm in [0, a].
__global__ void finalize1_kernel(const float* __restrict__ partmax,
                                 const float* __restrict__ basei,
                                 const float* __restrict__ posd,
                                 const int* __restrict__ valid,
                                 float* __restrict__ partials)
{
    const int tid = threadIdx.x;
    const int a   = blockIdx.x;
    const int row = a * 256 + tid;
    float m = -__builtin_inff();
    for (int bn = 2 * a; bn < 64; ++bn)
        m = fmaxf(m, partmax[(size_t)bn * NROWS + row]);
    for (int bm2 = 0; bm2 <= a; ++bm2)
        m = fmaxf(m, partmax[(size_t)(64 + bm2) * NROWS + row]);
    const float d2 = m + basei[row];
    const float mn = sqrtf(fmaxf(d2, 0.f));
    float loss = fmaxf(posd[row] - mn + MARGIN, 0.f);
    float cnt = 1.f;
    if (!valid[row]) { loss = 0.f; cnt = 0.f; }
    #pragma unroll
    for (int off = 32; off >= 1; off >>= 1) {
        loss += __shfl_xor(loss, off);
        cnt  += __shfl_xor(cnt, off);
    }
    __shared__ float sl[4], sc[4];
    const int w = tid >> 6, lane = tid & 63;
    if (lane == 0) { sl[w] = loss; sc[w] = cnt; }
    __syncthreads();
    if (tid == 0) {
        partials[blockIdx.x * 2]     = sl[0] + sl[1] + sl[2] + sl[3];
        partials[blockIdx.x * 2 + 1] = sc[0] + sc[1] + sc[2] + sc[3];
    }
}

// ---------------- kernel 4: final scalar ----------------
__global__ void finalize2_kernel(const float* __restrict__ partials, float* __restrict__ out)
{
    const int tid = threadIdx.x;   // 64 threads
    float l = 0.f, c = 0.f;
    if (tid < 32) { l = partials[tid * 2]; c = partials[tid * 2 + 1]; }
    #pragma unroll
    for (int off = 32; off >= 1; off >>= 1) {
        l += __shfl_xor(l, off);
        c += __shfl_xor(c, off);
    }
    if (tid == 0) out[0] = l / c;
}

extern "C" void kernel_launch(void* const* d_in, const int* in_sizes, int n_in,
                              void* d_out, int out_size, void* d_ws, size_t ws_size,
                              hipStream_t stream)
{
    const float* X = (const float*)d_in[0];   // [8192,1024] f32
    const float* P = (const float*)d_in[1];   // [1024] f32
    float* out = (float*)d_out;
    char* ws = (char*)d_ws;

    unsigned short* Xb = (unsigned short*)ws;                                // 16 MB bf16
    size_t off = (size_t)NROWS * DIM * sizeof(unsigned short);
    float* cj    = (float*)(ws + off);  off += (size_t)NROWS * 4;
    float* basei = (float*)(ws + off);  off += (size_t)NROWS * 4;
    float* posd  = (float*)(ws + off);  off += (size_t)NROWS * 4;
    int*   valid = (int*)(ws + off);    off += (size_t)NROWS * 4;
    float* partmax = (float*)(ws + off); off += (size_t)96 * NROWS * 4;      // 3 MB
    float* partials = (float*)(ws + off);

    prep_kernel<<<NROWS / 4, 256, 0, stream>>>(X, P, Xb, cj, basei, posd, valid);
    gemm_max_kernel<<<NUNITS, 512, 0, stream>>>(Xb, cj, partmax);
    finalize1_kernel<<<NROWS / 256, 256, 0, stream>>>(partmax, basei, posd, valid, partials);
    finalize2_kernel<<<1, 64, 0, stream>>>(partials, out);
}

// Round 13
// 121.366 us; speedup vs baseline: 1.6949x; 1.6949x over previous
//
#include <hip/hip_runtime.h>
#include <hip/hip_bf16.h>

// BatchTripletLoss on MI355X — round 13: R10 + 3-buf rotation + counted vmcnt.
// Units: 256x128 (bm<32, bn in [2bm,64) -> 1056), 8 waves (4M x 2N), 64x64/wave,
// BK=32, THREE buffers (72KB LDS) -> still 2 blocks/CU. Per KT:
//   STAGE((kt+2)%3); vmcnt(6); s_barrier; [8 ds_reads; 16 MFMA]; s_barrier.
// vmcnt(6): each STAGE = 3 vmem insts; leaving newest 6 (kt+1,kt+2) in flight
// guarantees kt's stage (9 back) landed; barrier makes that true for ALL waves.
// WAR: stage target (kt+2)%3 == (kt-1)%3, last read at kt-1, sealed by the
// end-barrier of kt-1 (one barrier before this STAGE issues). Never vmcnt(0)
// mid-loop (T4); raw s_barrier avoids __syncthreads' full drain.

#define NROWS 8192
#define DIM   1024
#define BTM   256
#define BTN   128
#define BK    32
#define NKT   (DIM / BK)            // 32 K-tiles
#define NUNITS 1056                 // sum_{bm<32} (64 - 2*bm)

constexpr float EPS = 1e-6f;
constexpr float MARGIN = 0.5f;

typedef __attribute__((ext_vector_type(8))) short short8;
typedef __attribute__((ext_vector_type(4))) float f32x4;

__device__ __forceinline__ unsigned short f2bf_rne(float f) {
    unsigned u = __float_as_uint(f);
    u += 0x7fffu + ((u >> 16) & 1u);
    return (unsigned short)(u >> 16);
}

// ---------------- kernel 1: per-row stats + bf16 conversion ----------------
__global__ void prep_kernel(const float* __restrict__ X, const float* __restrict__ P,
                            unsigned short* __restrict__ Xb,
                            float* __restrict__ cj, float* __restrict__ basei,
                            float* __restrict__ posd, int* __restrict__ valid)
{
    const int tid  = threadIdx.x;
    const int w    = tid >> 6;
    const int lane = tid & 63;
    const int row  = blockIdx.x * 4 + w;
    const float* xr = X + (size_t)row * DIM;

    float sq = 0.f, sm = 0.f, pd = 0.f;
    bool eq = true;
    #pragma unroll
    for (int it = 0; it < 4; ++it) {
        const int idx = it * 256 + lane * 4;
        const float4 x = *(const float4*)(xr + idx);
        const float4 p = *(const float4*)(P + idx);
        sq += x.x*x.x + x.y*x.y + x.z*x.z + x.w*x.w;
        sm += x.x + x.y + x.z + x.w;
        const float d0 = x.x - p.x + EPS, d1 = x.y - p.y + EPS;
        const float d2 = x.z - p.z + EPS, d3 = x.w - p.w + EPS;
        pd += d0*d0 + d1*d1 + d2*d2 + d3*d3;
        eq = eq && (x.x == p.x) && (x.y == p.y) && (x.z == p.z) && (x.w == p.w);
        ushort4 b;
        b.x = f2bf_rne(x.x); b.y = f2bf_rne(x.y); b.z = f2bf_rne(x.z); b.w = f2bf_rne(x.w);
        *(ushort4*)(Xb + (size_t)row * DIM + idx) = b;
    }
    #pragma unroll
    for (int off = 32; off >= 1; off >>= 1) {
        sq += __shfl_xor(sq, off);
        sm += __shfl_xor(sm, off);
        pd += __shfl_xor(pd, off);
    }
    const bool alleq = __all(eq);
    if (lane == 0) {
        cj[row]    = sq - 2.f * EPS * sm;
        basei[row] = sq + 2.f * EPS * sm + (float)DIM * EPS * EPS;
        posd[row]  = sqrtf(pd);
        valid[row] = alleq ? 0 : 1;
    }
}

// ---------------- kernel 2: co-resident symmetric GEMM + row/col max ----------------
// LDS per buf: A = 1024 chunks (16KB) + B = 512 chunks (8KB). Swizzle: logical (r,c)
// chunk at phys p = r*4 + (c ^ ((r>>1)&3)); gload_lds writes phys-linear, source
// pre-permuted (thread q -> row q>>2, K-chunk (q&3)^((q>>3)&3)). Frag reads:
// cx = lk ^ ((l15>>1)&3) -> conflict-free (verified R10: 0 conflicts).
__global__ __launch_bounds__(512, 4) void gemm_max_kernel(
        const unsigned short* __restrict__ Xb,
        const float* __restrict__ cj,
        float* __restrict__ partmax)
{
    __shared__ alignas(16) unsigned short lds[3][1536 * 8];   // [buf][A:0..1023 | B:1024..1535 chunks]

    const int tid  = threadIdx.x;
    const int lane = tid & 63;
    const int wid  = tid >> 6;        // 0..7
    const int wm   = wid >> 1;        // 0..3  (64-row strip)
    const int wn   = wid & 1;         // 0..1  (64-col strip)
    const int l15  = lane & 15;
    const int lk   = lane >> 4;       // 0..3
    const int cx   = lk ^ ((l15 >> 1) & 3);

    // XCD-chunked bijective unit decode (1056 = 8 * 132); base(bm) = 65*bm - bm*bm
    const int t0 = (blockIdx.x & 7) * (NUNITS / 8) + (blockIdx.x >> 3);
    int bm = (int)(32.5f - sqrtf(1056.25f - (float)t0));
    if (bm < 0) bm = 0;
    if (bm > 31) bm = 31;
    while (bm > 0 && 65 * bm - bm * bm > t0) --bm;
    while (65 * (bm + 1) - (bm + 1) * (bm + 1) <= t0) ++bm;
    const int bn = 2 * bm + (t0 - (65 * bm - bm * bm));
    const int Mbase = bm * BTM, Nbase = bn * BTN;

    f32x4 acc[4][4];
    #pragma unroll
    for (int m = 0; m < 4; ++m)
        #pragma unroll
        for (int n = 0; n < 4; ++n)
            acc[m][n] = (f32x4){0.f, 0.f, 0.f, 0.f};

    // stage A (2 insts) + B (1 inst) for one KT into buffer BUF (3 vmem total)
    #define STAGE(BUF, KT) do {                                                               \
        _Pragma("unroll")                                                                     \
        for (int inst_ = 0; inst_ < 2; ++inst_) {                                             \
            const int q_ = inst_ * 512 + tid;                                                 \
            const int r_ = q_ >> 2;                                                           \
            const int c_ = (q_ & 3) ^ ((q_ >> 3) & 3);                                        \
            const unsigned short* src_ = Xb + (size_t)(Mbase + r_) * DIM + (KT) * BK + c_ * 8; \
            unsigned short* dst_ = &lds[BUF][(inst_ * 512 + wid * 64) * 8];                   \
            __builtin_amdgcn_global_load_lds((const __attribute__((address_space(1))) void*)src_, \
                                             (__attribute__((address_space(3))) void*)dst_, 16, 0, 0); \
        }                                                                                     \
        {                                                                                     \
            const int r_ = tid >> 2;                                                          \
            const int c_ = (tid & 3) ^ ((tid >> 3) & 3);                                      \
            const unsigned short* src_ = Xb + (size_t)(Nbase + r_) * DIM + (KT) * BK + c_ * 8; \
            unsigned short* dst_ = &lds[BUF][(1024 + wid * 64) * 8];                          \
            __builtin_amdgcn_global_load_lds((const __attribute__((address_space(1))) void*)src_, \
                                             (__attribute__((address_space(3))) void*)dst_, 16, 0, 0); \
        }                                                                                     \
    } while (0)

    // prologue: stage kt0 -> buf0, kt1 -> buf1 (6 vmem outstanding)
    STAGE(0, 0);
    STAGE(1, 1);

    for (int kt = 0; kt < NKT; ++kt) {
        const int rb = kt % 3;
        if (kt + 2 < NKT) STAGE((kt + 2) % 3, kt + 2);

        // counted wait: kt's 3 stage-loads are >=9 back once kt+1 (3) + kt+2 (3) are newest
        if (kt < NKT - 2)       asm volatile("s_waitcnt vmcnt(6)" ::: "memory");
        else if (kt == NKT - 2) asm volatile("s_waitcnt vmcnt(3)" ::: "memory");
        else                    asm volatile("s_waitcnt vmcnt(0)" ::: "memory");
        __builtin_amdgcn_s_barrier();            // all waves' kt-loads landed
        __builtin_amdgcn_sched_barrier(0);

        const unsigned short* Ab = &lds[rb][0];
        const unsigned short* Bb = &lds[rb][1024 * 8];
        short8 af[4], bf[4];
        #pragma unroll
        for (int mt = 0; mt < 4; ++mt)
            af[mt] = *(const short8*)(Ab + (((wm * 64 + mt * 16 + l15) << 2) + cx) * 8);
        #pragma unroll
        for (int nt = 0; nt < 4; ++nt)
            bf[nt] = *(const short8*)(Bb + (((wn * 64 + nt * 16 + l15) << 2) + cx) * 8);

        __builtin_amdgcn_s_setprio(1);
        #pragma unroll
        for (int mt = 0; mt < 4; ++mt)
            #pragma unroll
            for (int nt = 0; nt < 4; ++nt)
                acc[mt][nt] = __builtin_amdgcn_mfma_f32_16x16x32_bf16(af[mt], bf[nt], acc[mt][nt], 0, 0, 0);
        __builtin_amdgcn_s_setprio(0);

        __builtin_amdgcn_s_barrier();            // reads of buf rb done -> safe to overwrite at kt+1
        __builtin_amdgcn_sched_barrier(0);
    }
    #undef STAGE

    // ---- epilogue. C/D layout: col = l15, row = lk*4 + reg.
    // acc[m][n]: row wm*64 + m*16, col wn*64 + n*16. Mask only i==j; both paths always.
    float* scratchf = (float*)&lds[0][0];  // [0..511]: row (wn*256+lrow); [512..1023]: col
    float cv[4];
    #pragma unroll
    for (int n = 0; n < 4; ++n)
        cv[n] = cj[Nbase + wn * 64 + n * 16 + l15];

    float vt[4];
    #pragma unroll
    for (int n = 0; n < 4; ++n) vt[n] = -__builtin_inff();

    #pragma unroll
    for (int m = 0; m < 4; ++m) {
        #pragma unroll
        for (int r = 0; r < 4; ++r) {
            const int lrow = wm * 64 + m * 16 + lk * 4 + r;
            const int grow = Mbase + lrow;
            const float ci = cj[grow];
            float rv = -__builtin_inff();
            #pragma unroll
            for (int n = 0; n < 4; ++n) {
                const float dot2 = 2.f * acc[m][n][r];
                const bool dg = (grow == Nbase + wn * 64 + n * 16 + l15);
                float vr = cv[n] - dot2;
                float vc = ci - dot2;
                if (dg) { vr = -__builtin_inff(); vc = -__builtin_inff(); }
                rv = fmaxf(rv, vr);
                vt[n] = fmaxf(vt[n], vc);
            }
            #pragma unroll
            for (int off = 8; off >= 1; off >>= 1)
                rv = fmaxf(rv, __shfl_xor(rv, off));
            if (l15 == 0) scratchf[wn * 256 + lrow] = rv;
        }
    }
    #pragma unroll
    for (int n = 0; n < 4; ++n) {
        vt[n] = fmaxf(vt[n], __shfl_xor(vt[n], 16));
        vt[n] = fmaxf(vt[n], __shfl_xor(vt[n], 32));
        if (lk == 0) scratchf[512 + wm * 128 + wn * 64 + n * 16 + l15] = vt[n];
    }
    __syncthreads();

    if (tid < BTM) {
        partmax[(size_t)bn * NROWS + Mbase + tid] = fmaxf(scratchf[tid], scratchf[256 + tid]);
    } else if (tid < BTM + BTN) {
        const int c = tid - BTM;
        const float v = fmaxf(fmaxf(scratchf[512 + c], scratchf[640 + c]),
                              fmaxf(scratchf[768 + c], scratchf[896 + c]));
        partmax[(size_t)(64 + bm) * NROWS + Nbase + c] = v;
    }
}

// ---------------- kernel 3: per-row finalize + block partial sums ----------------
// Row i (strip a = i>>8): row-path slots bn in [2a, 64); col-path slots 64+bm, bm in [0, a].
__global__ void finalize1_kernel(const float* __restrict__ partmax,
                                 const float* __restrict__ basei,
                                 const float* __restrict__ posd,
                                 const int* __restrict__ valid,
                                 float* __restrict__ partials)
{
    const int tid = threadIdx.x;
    const int a   = blockIdx.x;
    const int row = a * 256 + tid;
    float m = -__builtin_inff();
    for (int bn = 2 * a; bn < 64; ++bn)
        m = fmaxf(m, partmax[(size_t)bn * NROWS + row]);
    for (int bm2 = 0; bm2 <= a; ++bm2)
        m = fmaxf(m, partmax[(size_t)(64 + bm2) * NROWS + row]);
    const float d2 = m + basei[row];
    const float mn = sqrtf(fmaxf(d2, 0.f));
    float loss = fmaxf(posd[row] - mn + MARGIN, 0.f);
    float cnt = 1.f;
    if (!valid[row]) { loss = 0.f; cnt = 0.f; }
    #pragma unroll
    for (int off = 32; off >= 1; off >>= 1) {
        loss += __shfl_xor(loss, off);
        cnt  += __shfl_xor(cnt, off);
    }
    __shared__ float sl[4], sc[4];
    const int w = tid >> 6, lane = tid & 63;
    if (lane == 0) { sl[w] = loss; sc[w] = cnt; }
    __syncthreads();
    if (tid == 0) {
        partials[blockIdx.x * 2]     = sl[0] + sl[1] + sl[2] + sl[3];
        partials[blockIdx.x * 2 + 1] = sc[0] + sc[1] + sc[2] + sc[3];
    }
}

// ---------------- kernel 4: final scalar ----------------
__global__ void finalize2_kernel(const float* __restrict__ partials, float* __restrict__ out)
{
    const int tid = threadIdx.x;   // 64 threads
    float l = 0.f, c = 0.f;
    if (tid < 32) { l = partials[tid * 2]; c = partials[tid * 2 + 1]; }
    #pragma unroll
    for (int off = 32; off >= 1; off >>= 1) {
        l += __shfl_xor(l, off);
        c += __shfl_xor(c, off);
    }
    if (tid == 0) out[0] = l / c;
}

extern "C" void kernel_launch(void* const* d_in, const int* in_sizes, int n_in,
                              void* d_out, int out_size, void* d_ws, size_t ws_size,
                              hipStream_t stream)
{
    const float* X = (const float*)d_in[0];   // [8192,1024] f32
    const float* P = (const float*)d_in[1];   // [1024] f32
    float* out = (float*)d_out;
    char* ws = (char*)d_ws;

    unsigned short* Xb = (unsigned short*)ws;                                // 16 MB bf16
    size_t off = (size_t)NROWS * DIM * sizeof(unsigned short);
    float* cj    = (float*)(ws + off);  off += (size_t)NROWS * 4;
    float* basei = (float*)(ws + off);  off += (size_t)NROWS * 4;
    float* posd  = (float*)(ws + off);  off += (size_t)NROWS * 4;
    int*   valid = (int*)(ws + off);    off += (size_t)NROWS * 4;
    float* partmax = (float*)(ws + off); off += (size_t)96 * NROWS * 4;      // 3 MB
    float* partials = (float*)(ws + off);

    prep_kernel<<<NROWS / 4, 256, 0, stream>>>(X, P, Xb, cj, basei, posd, valid);
    gemm_max_kernel<<<NUNITS, 512, 0, stream>>>(Xb, cj, partmax);
    finalize1_kernel<<<NROWS / 256, 256, 0, stream>>>(partmax, basei, posd, valid, partials);
    finalize2_kernel<<<1, 64, 0, stream>>>(partials, out);
}

// Round 14
// 115.893 us; speedup vs baseline: 1.7749x; 1.0472x over previous
//
#include <hip/hip_runtime.h>
#include <hip/hip_bf16.h>

// BatchTripletLoss on MI355X — round 14: de-phasing co-resident blocks.
// R13 base (256x128 units, 1056 grid, 8 waves 4Mx2N, BK=32, 3 LDS bufs, 2 blk/CU)
// with: (1) ONE barrier/KT: {vmcnt(3); s_barrier; STAGE((kt+2)%3); reads; MFMA}.
//   WAR: barrier@kt => all waves issued kt-1 MFMAs => their ds_reads of buffer
//   (kt-1)%3 == (kt+2)%3 returned => overwrite safe. RAW: vmcnt(3) pre-barrier
//   => each wave's kt stage-loads landed; barrier makes it true for all waves.
// (2) deterministic per-block s_sleep stagger (hash(blockIdx)&7 * ~128cyc) to
//   push the CU's two co-resident blocks off the in-phase LDS-storm fixed point.

#define NROWS 8192
#define DIM   1024
#define BTM   256
#define BTN   128
#define BK    32
#define NKT   (DIM / BK)            // 32 K-tiles
#define NUNITS 1056                 // sum_{bm<32} (64 - 2*bm)

constexpr float EPS = 1e-6f;
constexpr float MARGIN = 0.5f;

typedef __attribute__((ext_vector_type(8))) short short8;
typedef __attribute__((ext_vector_type(4))) float f32x4;

__device__ __forceinline__ unsigned short f2bf_rne(float f) {
    unsigned u = __float_as_uint(f);
    u += 0x7fffu + ((u >> 16) & 1u);
    return (unsigned short)(u >> 16);
}

// ---------------- kernel 1: per-row stats + bf16 conversion ----------------
__global__ void prep_kernel(const float* __restrict__ X, const float* __restrict__ P,
                            unsigned short* __restrict__ Xb,
                            float* __restrict__ cj, float* __restrict__ basei,
                            float* __restrict__ posd, int* __restrict__ valid)
{
    const int tid  = threadIdx.x;
    const int w    = tid >> 6;
    const int lane = tid & 63;
    const int row  = blockIdx.x * 4 + w;
    const float* xr = X + (size_t)row * DIM;

    float sq = 0.f, sm = 0.f, pd = 0.f;
    bool eq = true;
    #pragma unroll
    for (int it = 0; it < 4; ++it) {
        const int idx = it * 256 + lane * 4;
        const float4 x = *(const float4*)(xr + idx);
        const float4 p = *(const float4*)(P + idx);
        sq += x.x*x.x + x.y*x.y + x.z*x.z + x.w*x.w;
        sm += x.x + x.y + x.z + x.w;
        const float d0 = x.x - p.x + EPS, d1 = x.y - p.y + EPS;
        const float d2 = x.z - p.z + EPS, d3 = x.w - p.w + EPS;
        pd += d0*d0 + d1*d1 + d2*d2 + d3*d3;
        eq = eq && (x.x == p.x) && (x.y == p.y) && (x.z == p.z) && (x.w == p.w);
        ushort4 b;
        b.x = f2bf_rne(x.x); b.y = f2bf_rne(x.y); b.z = f2bf_rne(x.z); b.w = f2bf_rne(x.w);
        *(ushort4*)(Xb + (size_t)row * DIM + idx) = b;
    }
    #pragma unroll
    for (int off = 32; off >= 1; off >>= 1) {
        sq += __shfl_xor(sq, off);
        sm += __shfl_xor(sm, off);
        pd += __shfl_xor(pd, off);
    }
    const bool alleq = __all(eq);
    if (lane == 0) {
        cj[row]    = sq - 2.f * EPS * sm;
        basei[row] = sq + 2.f * EPS * sm + (float)DIM * EPS * EPS;
        posd[row]  = sqrtf(pd);
        valid[row] = alleq ? 0 : 1;
    }
}

// ---------------- kernel 2: co-resident symmetric GEMM + row/col max ----------------
// LDS per buf: A = 1024 chunks (16KB) + B = 512 chunks (8KB). Swizzle: logical (r,c)
// chunk at phys p = r*4 + (c ^ ((r>>1)&3)); gload_lds writes phys-linear, source
// pre-permuted (thread q -> row q>>2, K-chunk (q&3)^((q>>3)&3)). Frag reads:
// cx = lk ^ ((l15>>1)&3) -> conflict-free (verified R10/R13: 0 conflicts).
__global__ __launch_bounds__(512, 4) void gemm_max_kernel(
        const unsigned short* __restrict__ Xb,
        const float* __restrict__ cj,
        float* __restrict__ partmax)
{
    __shared__ alignas(16) unsigned short lds[3][1536 * 8];   // [buf][A:0..1023 | B:1024..1535 chunks]

    const int tid  = threadIdx.x;
    const int lane = tid & 63;
    const int wid  = tid >> 6;        // 0..7
    const int wm   = wid >> 1;        // 0..3  (64-row strip)
    const int wn   = wid & 1;         // 0..1  (64-col strip)
    const int l15  = lane & 15;
    const int lk   = lane >> 4;       // 0..3
    const int cx   = lk ^ ((l15 >> 1) & 3);

    // deterministic start stagger: hash(blockIdx)&7 sleeps of ~128cyc each
    {
        const unsigned h = ((unsigned)blockIdx.x * 2654435761u) >> 29;   // 0..7
        for (unsigned i = 0; i < h; ++i) __builtin_amdgcn_s_sleep(2);
    }

    // XCD-chunked bijective unit decode (1056 = 8 * 132); base(bm) = 65*bm - bm*bm
    const int t0 = (blockIdx.x & 7) * (NUNITS / 8) + (blockIdx.x >> 3);
    int bm = (int)(32.5f - sqrtf(1056.25f - (float)t0));
    if (bm < 0) bm = 0;
    if (bm > 31) bm = 31;
    while (bm > 0 && 65 * bm - bm * bm > t0) --bm;
    while (65 * (bm + 1) - (bm + 1) * (bm + 1) <= t0) ++bm;
    const int bn = 2 * bm + (t0 - (65 * bm - bm * bm));
    const int Mbase = bm * BTM, Nbase = bn * BTN;

    f32x4 acc[4][4];
    #pragma unroll
    for (int m = 0; m < 4; ++m)
        #pragma unroll
        for (int n = 0; n < 4; ++n)
            acc[m][n] = (f32x4){0.f, 0.f, 0.f, 0.f};

    // stage A (2 insts) + B (1 inst) for one KT into buffer BUF (3 vmem total)
    #define STAGE(BUF, KT) do {                                                               \
        _Pragma("unroll")                                                                     \
        for (int inst_ = 0; inst_ < 2; ++inst_) {                                             \
            const int q_ = inst_ * 512 + tid;                                                 \
            const int r_ = q_ >> 2;                                                           \
            const int c_ = (q_ & 3) ^ ((q_ >> 3) & 3);                                        \
            const unsigned short* src_ = Xb + (size_t)(Mbase + r_) * DIM + (KT) * BK + c_ * 8; \
            unsigned short* dst_ = &lds[BUF][(inst_ * 512 + wid * 64) * 8];                   \
            __builtin_amdgcn_global_load_lds((const __attribute__((address_space(1))) void*)src_, \
                                             (__attribute__((address_space(3))) void*)dst_, 16, 0, 0); \
        }                                                                                     \
        {                                                                                     \
            const int r_ = tid >> 2;                                                          \
            const int c_ = (tid & 3) ^ ((tid >> 3) & 3);                                      \
            const unsigned short* src_ = Xb + (size_t)(Nbase + r_) * DIM + (KT) * BK + c_ * 8; \
            unsigned short* dst_ = &lds[BUF][(1024 + wid * 64) * 8];                          \
            __builtin_amdgcn_global_load_lds((const __attribute__((address_space(1))) void*)src_, \
                                             (__attribute__((address_space(3))) void*)dst_, 16, 0, 0); \
        }                                                                                     \
    } while (0)

    // prologue: stage kt0 -> buf0, kt1 -> buf1 (6 vmem outstanding)
    STAGE(0, 0);
    STAGE(1, 1);

    for (int kt = 0; kt < NKT; ++kt) {
        const int rb = kt % 3;

        // counted wait: outstanding here = tiles kt (3) + kt+1 (3); keep 3 newest in flight
        if (kt < NKT - 1) asm volatile("s_waitcnt vmcnt(3)" ::: "memory");
        else              asm volatile("s_waitcnt vmcnt(0)" ::: "memory");
        __builtin_amdgcn_s_barrier();            // all waves' kt-loads landed; kt-1 reads returned
        __builtin_amdgcn_sched_barrier(0);

        // stage kt+2 into (kt+2)%3 == (kt-1)%3 — safe per barrier above
        if (kt + 2 < NKT) STAGE((kt + 2) % 3, kt + 2);

        const unsigned short* Ab = &lds[rb][0];
        const unsigned short* Bb = &lds[rb][1024 * 8];
        short8 af[4], bf[4];
        #pragma unroll
        for (int mt = 0; mt < 4; ++mt)
            af[mt] = *(const short8*)(Ab + (((wm * 64 + mt * 16 + l15) << 2) + cx) * 8);
        #pragma unroll
        for (int nt = 0; nt < 4; ++nt)
            bf[nt] = *(const short8*)(Bb + (((wn * 64 + nt * 16 + l15) << 2) + cx) * 8);

        __builtin_amdgcn_s_setprio(1);
        #pragma unroll
        for (int mt = 0; mt < 4; ++mt)
            #pragma unroll
            for (int nt = 0; nt < 4; ++nt)
                acc[mt][nt] = __builtin_amdgcn_mfma_f32_16x16x32_bf16(af[mt], bf[nt], acc[mt][nt], 0, 0, 0);
        __builtin_amdgcn_s_setprio(0);
        // no end barrier: next iteration's top barrier seals this KT
    }
    #undef STAGE

    // ---- epilogue. C/D layout: col = l15, row = lk*4 + reg.
    // acc[m][n]: row wm*64 + m*16, col wn*64 + n*16. Mask only i==j; both paths always.
    // scratch = buf0 head; buf0 last read at kt=30 — all waves passed barrier@31 => safe.
    float* scratchf = (float*)&lds[0][0];  // [0..511]: row (wn*256+lrow); [512..1023]: col
    float cv[4];
    #pragma unroll
    for (int n = 0; n < 4; ++n)
        cv[n] = cj[Nbase + wn * 64 + n * 16 + l15];

    float vt[4];
    #pragma unroll
    for (int n = 0; n < 4; ++n) vt[n] = -__builtin_inff();

    #pragma unroll
    for (int m = 0; m < 4; ++m) {
        #pragma unroll
        for (int r = 0; r < 4; ++r) {
            const int lrow = wm * 64 + m * 16 + lk * 4 + r;
            const int grow = Mbase + lrow;
            const float ci = cj[grow];
            float rv = -__builtin_inff();
            #pragma unroll
            for (int n = 0; n < 4; ++n) {
                const float dot2 = 2.f * acc[m][n][r];
                const bool dg = (grow == Nbase + wn * 64 + n * 16 + l15);
                float vr = cv[n] - dot2;
                float vc = ci - dot2;
                if (dg) { vr = -__builtin_inff(); vc = -__builtin_inff(); }
                rv = fmaxf(rv, vr);
                vt[n] = fmaxf(vt[n], vc);
            }
            #pragma unroll
            for (int off = 8; off >= 1; off >>= 1)
                rv = fmaxf(rv, __shfl_xor(rv, off));
            if (l15 == 0) scratchf[wn * 256 + lrow] = rv;
        }
    }
    #pragma unroll
    for (int n = 0; n < 4; ++n) {
        vt[n] = fmaxf(vt[n], __shfl_xor(vt[n], 16));
        vt[n] = fmaxf(vt[n], __shfl_xor(vt[n], 32));
        if (lk == 0) scratchf[512 + wm * 128 + wn * 64 + n * 16 + l15] = vt[n];
    }
    __syncthreads();

    if (tid < BTM) {
        partmax[(size_t)bn * NROWS + Mbase + tid] = fmaxf(scratchf[tid], scratchf[256 + tid]);
    } else if (tid < BTM + BTN) {
        const int c = tid - BTM;
        const float v = fmaxf(fmaxf(scratchf[512 + c], scratchf[640 + c]),
                              fmaxf(scratchf[768 + c], scratchf[896 + c]));
        partmax[(size_t)(64 + bm) * NROWS + Nbase + c] = v;
    }
}

// ---------------- kernel 3: per-row finalize + block partial sums ----------------
// Row i (strip a = i>>8): row-path slots bn in [2a, 64); col-path slots 64+bm, bm in [0, a].
__global__ void finalize1_kernel(const float* __restrict__ partmax,
                                 const float* __restrict__ basei,
                                 const float* __restrict__ posd,
                                 const int* __restrict__ valid,
                                 float* __restrict__ partials)
{
    const int tid = threadIdx.x;
    const int a   = blockIdx.x;
    const int row = a * 256 + tid;
    float m = -__builtin_inff();
    for (int bn = 2 * a; bn < 64; ++bn)
        m = fmaxf(m, partmax[(size_t)bn * NROWS + row]);
    for (int bm2 = 0; bm2 <= a; ++bm2)
        m = fmaxf(m, partmax[(size_t)(64 + bm2) * NROWS + row]);
    const float d2 = m + basei[row];
    const float mn = sqrtf(fmaxf(d2, 0.f));
    float loss = fmaxf(posd[row] - mn + MARGIN, 0.f);
    float cnt = 1.f;
    if (!valid[row]) { loss = 0.f; cnt = 0.f; }
    #pragma unroll
    for (int off = 32; off >= 1; off >>= 1) {
        loss += __shfl_xor(loss, off);
        cnt  += __shfl_xor(cnt, off);
    }
    __shared__ float sl[4], sc[4];
    const int w = tid >> 6, lane = tid & 63;
    if (lane == 0) { sl[w] = loss; sc[w] = cnt; }
    __syncthreads();
    if (tid == 0) {
        partials[blockIdx.x * 2]     = sl[0] + sl[1] + sl[2] + sl[3];
        partials[blockIdx.x * 2 + 1] = sc[0] + sc[1] + sc[2] + sc[3];
    }
}

// ---------------- kernel 4: final scalar ----------------
__global__ void finalize2_kernel(const float* __restrict__ partials, float* __restrict__ out)
{
    const int tid = threadIdx.x;   // 64 threads
    float l = 0.f, c = 0.f;
    if (tid < 32) { l = partials[tid * 2]; c = partials[tid * 2 + 1]; }
    #pragma unroll
    for (int off = 32; off >= 1; off >>= 1) {
        l += __shfl_xor(l, off);
        c += __shfl_xor(c, off);
    }
    if (tid == 0) out[0] = l / c;
}

extern "C" void kernel_launch(void* const* d_in, const int* in_sizes, int n_in,
                              void* d_out, int out_size, void* d_ws, size_t ws_size,
                              hipStream_t stream)
{
    const float* X = (const float*)d_in[0];   // [8192,1024] f32
    const float* P = (const float*)d_in[1];   // [1024] f32
    float* out = (float*)d_out;
    char* ws = (char*)d_ws;

    unsigned short* Xb = (unsigned short*)ws;                                // 16 MB bf16
    size_t off = (size_t)NROWS * DIM * sizeof(unsigned short);
    float* cj    = (float*)(ws + off);  off += (size_t)NROWS * 4;
    float* basei = (float*)(ws + off);  off += (size_t)NROWS * 4;
    float* posd  = (float*)(ws + off);  off += (size_t)NROWS * 4;
    int*   valid = (int*)(ws + off);    off += (size_t)NROWS * 4;
    float* partmax = (float*)(ws + off); off += (size_t)96 * NROWS * 4;      // 3 MB
    float* partials = (float*)(ws + off);

    prep_kernel<<<NROWS / 4, 256, 0, stream>>>(X, P, Xb, cj, basei, posd, valid);
    gemm_max_kernel<<<NUNITS, 512, 0, stream>>>(Xb, cj, partmax);
    finalize1_kernel<<<NROWS / 256, 256, 0, stream>>>(partmax, basei, posd, valid, partials);
    finalize2_kernel<<<1, 64, 0, stream>>>(partials, out);
}

// Round 15
// 112.489 us; speedup vs baseline: 1.8286x; 1.0303x over previous
//
#include <hip/hip_runtime.h>
#include <hip/hip_bf16.h>

// BatchTripletLoss on MI355X — round 15: R14 + constant-folded steady-state addressing.
// Identical sync structure to R14 (one barrier/KT, counted vmcnt(3), 3 LDS bufs,
// 2 blk/CU, s_sleep stagger). KT loop unrolled x3 so the buffer index is
// compile-time: ds_reads become base+imm (aoff/boff computed once), staging uses
// 3 persistent per-thread src pointers (+64B/KT) and static LDS destinations.
// Mechanism: kill the ~26% VALUBusy of per-KT runtime address math that competes
// with MFMA/ds_read issue slots.

#define NROWS 8192
#define DIM   1024
#define BTM   256
#define BTN   128
#define BK    32
#define NKT   (DIM / BK)            // 32 K-tiles
#define NUNITS 1056                 // sum_{bm<32} (64 - 2*bm)

constexpr float EPS = 1e-6f;
constexpr float MARGIN = 0.5f;

typedef __attribute__((ext_vector_type(8))) short short8;
typedef __attribute__((ext_vector_type(4))) float f32x4;

__device__ __forceinline__ unsigned short f2bf_rne(float f) {
    unsigned u = __float_as_uint(f);
    u += 0x7fffu + ((u >> 16) & 1u);
    return (unsigned short)(u >> 16);
}

// ---------------- kernel 1: per-row stats + bf16 conversion ----------------
__global__ void prep_kernel(const float* __restrict__ X, const float* __restrict__ P,
                            unsigned short* __restrict__ Xb,
                            float* __restrict__ cj, float* __restrict__ basei,
                            float* __restrict__ posd, int* __restrict__ valid)
{
    const int tid  = threadIdx.x;
    const int w    = tid >> 6;
    const int lane = tid & 63;
    const int row  = blockIdx.x * 4 + w;
    const float* xr = X + (size_t)row * DIM;

    float sq = 0.f, sm = 0.f, pd = 0.f;
    bool eq = true;
    #pragma unroll
    for (int it = 0; it < 4; ++it) {
        const int idx = it * 256 + lane * 4;
        const float4 x = *(const float4*)(xr + idx);
        const float4 p = *(const float4*)(P + idx);
        sq += x.x*x.x + x.y*x.y + x.z*x.z + x.w*x.w;
        sm += x.x + x.y + x.z + x.w;
        const float d0 = x.x - p.x + EPS, d1 = x.y - p.y + EPS;
        const float d2 = x.z - p.z + EPS, d3 = x.w - p.w + EPS;
        pd += d0*d0 + d1*d1 + d2*d2 + d3*d3;
        eq = eq && (x.x == p.x) && (x.y == p.y) && (x.z == p.z) && (x.w == p.w);
        ushort4 b;
        b.x = f2bf_rne(x.x); b.y = f2bf_rne(x.y); b.z = f2bf_rne(x.z); b.w = f2bf_rne(x.w);
        *(ushort4*)(Xb + (size_t)row * DIM + idx) = b;
    }
    #pragma unroll
    for (int off = 32; off >= 1; off >>= 1) {
        sq += __shfl_xor(sq, off);
        sm += __shfl_xor(sm, off);
        pd += __shfl_xor(pd, off);
    }
    const bool alleq = __all(eq);
    if (lane == 0) {
        cj[row]    = sq - 2.f * EPS * sm;
        basei[row] = sq + 2.f * EPS * sm + (float)DIM * EPS * EPS;
        posd[row]  = sqrtf(pd);
        valid[row] = alleq ? 0 : 1;
    }
}

// ---------------- kernel 2: co-resident symmetric GEMM + row/col max ----------------
// LDS per buf: A = 1024 chunks (16KB) + B = 512 chunks (8KB). Swizzle: logical (r,c)
// chunk at phys p = r*4 + (c ^ ((r>>1)&3)); gload_lds writes phys-linear, source
// pre-permuted (thread q -> row q>>2, K-chunk (q&3)^((q>>3)&3)). Frag reads:
// cx = lk ^ ((l15>>1)&3) -> conflict-free (verified R10/R13/R14: 0 conflicts).
__global__ __launch_bounds__(512, 4) void gemm_max_kernel(
        const unsigned short* __restrict__ Xb,
        const float* __restrict__ cj,
        float* __restrict__ partmax)
{
    __shared__ alignas(16) unsigned short lds[3][1536 * 8];   // [buf][A:0..1023 | B:1024..1535 chunks]

    const int tid  = threadIdx.x;
    const int lane = tid & 63;
    const int wid  = tid >> 6;        // 0..7
    const int wm   = wid >> 1;        // 0..3  (64-row strip)
    const int wn   = wid & 1;         // 0..1  (64-col strip)
    const int l15  = lane & 15;
    const int lk   = lane >> 4;       // 0..3
    const int cx   = lk ^ ((l15 >> 1) & 3);

    // deterministic start stagger: hash(blockIdx)&7 sleeps of ~128cyc each
    {
        const unsigned h = ((unsigned)blockIdx.x * 2654435761u) >> 29;   // 0..7
        for (unsigned i = 0; i < h; ++i) __builtin_amdgcn_s_sleep(2);
    }

    // XCD-chunked bijective unit decode (1056 = 8 * 132); base(bm) = 65*bm - bm*bm
    const int t0 = (blockIdx.x & 7) * (NUNITS / 8) + (blockIdx.x >> 3);
    int bm = (int)(32.5f - sqrtf(1056.25f - (float)t0));
    if (bm < 0) bm = 0;
    if (bm > 31) bm = 31;
    while (bm > 0 && 65 * bm - bm * bm > t0) --bm;
    while (65 * (bm + 1) - (bm + 1) * (bm + 1) <= t0) ++bm;
    const int bn = 2 * bm + (t0 - (65 * bm - bm * bm));
    const int Mbase = bm * BTM, Nbase = bn * BTN;

    f32x4 acc[4][4];
    #pragma unroll
    for (int m = 0; m < 4; ++m)
        #pragma unroll
        for (int n = 0; n < 4; ++n)
            acc[m][n] = (f32x4){0.f, 0.f, 0.f, 0.f};

    // ---- persistent per-thread staging sources (advance +BK elements per staged KT)
    const int qa0 = tid,        ra0 = qa0 >> 2, ca0 = (qa0 & 3) ^ ((qa0 >> 3) & 3);
    const int qa1 = 512 + tid,  ra1 = qa1 >> 2, ca1 = (qa1 & 3) ^ ((qa1 >> 3) & 3);
    const unsigned short* sA0 = Xb + (size_t)(Mbase + ra0) * DIM + ca0 * 8;
    const unsigned short* sA1 = Xb + (size_t)(Mbase + ra1) * DIM + ca1 * 8;
    const unsigned short* sB0 = Xb + (size_t)(Nbase + ra0) * DIM + ca0 * 8;

    // stage tile KT into buffer SB from the persistent pointers + KT*BK
    #define STAGE_K(SB, KT) do {                                                              \
        __builtin_amdgcn_global_load_lds((const __attribute__((address_space(1))) void*)(sA0 + (KT) * BK), \
                (__attribute__((address_space(3))) void*)(&lds[SB][(wid * 64) * 8]), 16, 0, 0); \
        __builtin_amdgcn_global_load_lds((const __attribute__((address_space(1))) void*)(sA1 + (KT) * BK), \
                (__attribute__((address_space(3))) void*)(&lds[SB][(512 + wid * 64) * 8]), 16, 0, 0); \
        __builtin_amdgcn_global_load_lds((const __attribute__((address_space(1))) void*)(sB0 + (KT) * BK), \
                (__attribute__((address_space(3))) void*)(&lds[SB][(1024 + wid * 64) * 8]), 16, 0, 0); \
    } while (0)

    // ---- frag-read base offsets (ushort units), computed once
    const int aoff = ((wm * 64 + l15) * 4 + cx) * 8;
    const int boff = 1024 * 8 + ((wn * 64 + l15) * 4 + cx) * 8;

    // one KT iteration: RB = buffer to read (const), SB = buffer to stage (const),
    // KTS = tile index to stage (runtime ok: folds to ptr+imm inside unrolled loop)
    #define KT_BODY(RB, SB, KTS, VMC, DOSTAGE) do {                                           \
        asm volatile("s_waitcnt vmcnt(" #VMC ")" ::: "memory");                               \
        __builtin_amdgcn_s_barrier();                                                         \
        __builtin_amdgcn_sched_barrier(0);                                                    \
        if (DOSTAGE) STAGE_K(SB, KTS);                                                        \
        short8 af[4], bf[4];                                                                  \
        _Pragma("unroll")                                                                     \
        for (int mt = 0; mt < 4; ++mt)                                                        \
            af[mt] = *(const short8*)(&lds[RB][0] + aoff + mt * 512);                         \
        _Pragma("unroll")                                                                     \
        for (int nt = 0; nt < 4; ++nt)                                                        \
            bf[nt] = *(const short8*)(&lds[RB][0] + boff + nt * 512);                         \
        __builtin_amdgcn_s_setprio(1);                                                        \
        _Pragma("unroll")                                                                     \
        for (int mt = 0; mt < 4; ++mt)                                                        \
            _Pragma("unroll")                                                                 \
            for (int nt = 0; nt < 4; ++nt)                                                    \
                acc[mt][nt] = __builtin_amdgcn_mfma_f32_16x16x32_bf16(af[mt], bf[nt], acc[mt][nt], 0, 0, 0); \
        __builtin_amdgcn_s_setprio(0);                                                        \
    } while (0)

    // prologue: stage kt0 -> buf0, kt1 -> buf1 (6 vmem outstanding)
    STAGE_K(0, 0);
    STAGE_K(1, 1);

    // main: kt = 0..29 (stages tiles 2..31); buffer indices compile-time via x3 unroll
    for (int ktb = 0; ktb < 30; ktb += 3) {
        KT_BODY(0, 2, ktb + 2, 3, true);
        KT_BODY(1, 0, ktb + 3, 3, true);
        KT_BODY(2, 1, ktb + 4, 3, true);
    }
    // tail: kt = 30 (rb 0), kt = 31 (rb 1), no staging
    KT_BODY(0, 2, 0, 3, false);
    KT_BODY(1, 2, 0, 0, false);
    #undef KT_BODY
    #undef STAGE_K

    // ---- epilogue. C/D layout: col = l15, row = lk*4 + reg.
    // acc[m][n]: row wm*64 + m*16, col wn*64 + n*16. Mask only i==j; both paths always.
    // scratch = buf0 head; buf0 last read at kt=30 — all waves passed barrier@31 => safe.
    float* scratchf = (float*)&lds[0][0];  // [0..511]: row (wn*256+lrow); [512..1023]: col
    float cv[4];
    #pragma unroll
    for (int n = 0; n < 4; ++n)
        cv[n] = cj[Nbase + wn * 64 + n * 16 + l15];

    float vt[4];
    #pragma unroll
    for (int n = 0; n < 4; ++n) vt[n] = -__builtin_inff();

    #pragma unroll
    for (int m = 0; m < 4; ++m) {
        #pragma unroll
        for (int r = 0; r < 4; ++r) {
            const int lrow = wm * 64 + m * 16 + lk * 4 + r;
            const int grow = Mbase + lrow;
            const float ci = cj[grow];
            float rv = -__builtin_inff();
            #pragma unroll
            for (int n = 0; n < 4; ++n) {
                const float dot2 = 2.f * acc[m][n][r];
                const bool dg = (grow == Nbase + wn * 64 + n * 16 + l15);
                float vr = cv[n] - dot2;
                float vc = ci - dot2;
                if (dg) { vr = -__builtin_inff(); vc = -__builtin_inff(); }
                rv = fmaxf(rv, vr);
                vt[n] = fmaxf(vt[n], vc);
            }
            #pragma unroll
            for (int off = 8; off >= 1; off >>= 1)
                rv = fmaxf(rv, __shfl_xor(rv, off));
            if (l15 == 0) scratchf[wn * 256 + lrow] = rv;
        }
    }
    #pragma unroll
    for (int n = 0; n < 4; ++n) {
        vt[n] = fmaxf(vt[n], __shfl_xor(vt[n], 16));
        vt[n] = fmaxf(vt[n], __shfl_xor(vt[n], 32));
        if (lk == 0) scratchf[512 + wm * 128 + wn * 64 + n * 16 + l15] = vt[n];
    }
    __syncthreads();

    if (tid < BTM) {
        partmax[(size_t)bn * NROWS + Mbase + tid] = fmaxf(scratchf[tid], scratchf[256 + tid]);
    } else if (tid < BTM + BTN) {
        const int c = tid - BTM;
        const float v = fmaxf(fmaxf(scratchf[512 + c], scratchf[640 + c]),
                              fmaxf(scratchf[768 + c], scratchf[896 + c]));
        partmax[(size_t)(64 + bm) * NROWS + Nbase + c] = v;
    }
}

// ---------------- kernel 3: per-row finalize + block partial sums ----------------
// Row i (strip a = i>>8): row-path slots bn in [2a, 64); col-path slots 64+bm, bm in [0, a].
__global__ void finalize1_kernel(const float* __restrict__ partmax,
                                 const float* __restrict__ basei,
                                 const float* __restrict__ posd,
                                 const int* __restrict__ valid,
                                 float* __restrict__ partials)
{
    const int tid = threadIdx.x;
    const int a   = blockIdx.x;
    const int row = a * 256 + tid;
    float m = -__builtin_inff();
    for (int bn = 2 * a; bn < 64; ++bn)
        m = fmaxf(m, partmax[(size_t)bn * NROWS + row]);
    for (int bm2 = 0; bm2 <= a; ++bm2)
        m = fmaxf(m, partmax[(size_t)(64 + bm2) * NROWS + row]);
    const float d2 = m + basei[row];
    const float mn = sqrtf(fmaxf(d2, 0.f));
    float loss = fmaxf(posd[row] - mn + MARGIN, 0.f);
    float cnt = 1.f;
    if (!valid[row]) { loss = 0.f; cnt = 0.f; }
    #pragma unroll
    for (int off = 32; off >= 1; off >>= 1) {
        loss += __shfl_xor(loss, off);
        cnt  += __shfl_xor(cnt, off);
    }
    __shared__ float sl[4], sc[4];
    const int w = tid >> 6, lane = tid & 63;
    if (lane == 0) { sl[w] = loss; sc[w] = cnt; }
    __syncthreads();
    if (tid == 0) {
        partials[blockIdx.x * 2]     = sl[0] + sl[1] + sl[2] + sl[3];
        partials[blockIdx.x * 2 + 1] = sc[0] + sc[1] + sc[2] + sc[3];
    }
}

// ---------------- kernel 4: final scalar ----------------
__global__ void finalize2_kernel(const float* __restrict__ partials, float* __restrict__ out)
{
    const int tid = threadIdx.x;   // 64 threads
    float l = 0.f, c = 0.f;
    if (tid < 32) { l = partials[tid * 2]; c = partials[tid * 2 + 1]; }
    #pragma unroll
    for (int off = 32; off >= 1; off >>= 1) {
        l += __shfl_xor(l, off);
        c += __shfl_xor(c, off);
    }
    if (tid == 0) out[0] = l / c;
}

extern "C" void kernel_launch(void* const* d_in, const int* in_sizes, int n_in,
                              void* d_out, int out_size, void* d_ws, size_t ws_size,
                              hipStream_t stream)
{
    const float* X = (const float*)d_in[0];   // [8192,1024] f32
    const float* P = (const float*)d_in[1];   // [1024] f32
    float* out = (float*)d_out;
    char* ws = (char*)d_ws;

    unsigned short* Xb = (unsigned short*)ws;                                // 16 MB bf16
    size_t off = (size_t)NROWS * DIM * sizeof(unsigned short);
    float* cj    = (float*)(ws + off);  off += (size_t)NROWS * 4;
    float* basei = (float*)(ws + off);  off += (size_t)NROWS * 4;
    float* posd  = (float*)(ws + off);  off += (size_t)NROWS * 4;
    int*   valid = (int*)(ws + off);    off += (size_t)NROWS * 4;
    float* partmax = (float*)(ws + off); off += (size_t)96 * NROWS * 4;      // 3 MB
    float* partials = (float*)(ws + off);

    prep_kernel<<<NROWS / 4, 256, 0, stream>>>(X, P, Xb, cj, basei, posd, valid);
    gemm_max_kernel<<<NUNITS, 512, 0, stream>>>(Xb, cj, partmax);
    finalize1_kernel<<<NROWS / 256, 256, 0, stream>>>(partmax, basei, posd, valid, partials);
    finalize2_kernel<<<1, 64, 0, stream>>>(partials, out);
}